// Round 4
// baseline (25653.699 us; speedup 1.0000x reference)
//
#include <hip/hip_runtime.h>

typedef unsigned short ushort_t;
typedef __attribute__((ext_vector_type(8))) short short8;
typedef __attribute__((ext_vector_type(4))) float f32x4;
typedef __attribute__((ext_vector_type(4))) int i32x4;

#define NB   256     // batch
#define NT   512     // timesteps
#define ND   512     // input dim
#define NH   1024    // hidden dim
#define KK   1536    // NH + ND (concatenated K)

#define GROUPS      4    // independent batch groups
#define ROWS_PER_G  64   // batch rows per group
#define BLKS_PER_G  64   // blocks per group (n-partitions)
#define KW          384  // K-range per wave (4-way K-split)
#define KS          12   // K-steps of 32 per wave

__device__ __forceinline__ ushort_t f2bf(float f) {
  union { float f; unsigned u; } v; v.f = f;
  unsigned u = v.u;
  return (ushort_t)((u + 0x7FFFu + ((u >> 16) & 1u)) >> 16);
}
__device__ __forceinline__ int pack2(float a, float b) {
  return (int)(((unsigned)f2bf(b) << 16) | (unsigned)f2bf(a));
}
__device__ __forceinline__ float sigmoidf_(float x) {
  return 1.f / (1.f + __expf(-x));
}
__device__ __forceinline__ float tanhf_(float x) {
  return 1.f - 2.f / (__expf(2.f * x) + 1.f);
}

// ---------------------------------------------------------------------------
// Repack weights to bf16, N-major (k-contiguous). Verified in round 2.
//   B1t [2048][1536]: cols 0..1023 = z ([U_z;W_z]), 1024..2047 = r ([U_r;W_r])
//   B2t [1024][1536]: candidate ([U;W])
// ---------------------------------------------------------------------------
__global__ void repack_weights(const float* __restrict__ U,  const float* __restrict__ W,
                               const float* __restrict__ Uz, const float* __restrict__ Wz,
                               const float* __restrict__ Ur, const float* __restrict__ Wr,
                               ushort_t* __restrict__ B1t, ushort_t* __restrict__ B2t) {
  const int kt = blockIdx.x, nt = blockIdx.y, which = blockIdx.z;
  if (which == 1 && nt >= 16) return;
  __shared__ float tile[64][65];
  const int k0 = kt * 64, n0 = nt * 64;
  const int tid = threadIdx.x;
  for (int i = 0; i < 16; ++i) {
    int e = tid + i * 256;
    int r = e >> 6, c = e & 63;
    int k = k0 + r, n = n0 + c;
    int nn = n & 1023;
    const float* src;
    if (which == 0) {
      if (k < NH) src = (n < NH ? Uz : Ur) + (size_t)k * NH + nn;
      else        src = (n < NH ? Wz : Wr) + (size_t)(k - NH) * NH + nn;
    } else {
      if (k < NH) src = U + (size_t)k * NH + nn;
      else        src = W + (size_t)(k - NH) * NH + nn;
    }
    tile[r][c] = *src;
  }
  __syncthreads();
  ushort_t* dst = (which == 0) ? B1t : B2t;
  for (int i = 0; i < 2; ++i) {
    int cch = tid + i * 256;
    int nl = cch >> 3, kc = (cch & 7) * 8;
    ushort_t tmp[8];
#pragma unroll
    for (int j = 0; j < 8; ++j) tmp[j] = f2bf(tile[kc + j][nl]);
    *reinterpret_cast<i32x4*>(dst + (size_t)(n0 + nl) * KK + k0 + kc) =
        *reinterpret_cast<i32x4*>(tmp);
  }
}

__global__ void init_state(ushort_t* __restrict__ hb, float* __restrict__ hf,
                           unsigned* __restrict__ flags) {
  int i = blockIdx.x * 256 + threadIdx.x;   // grid 1024 -> 262144 threads
  if (i < NB * NH) { hb[i] = 0; hf[i] = 0.f; }
  if (i < GROUPS * BLKS_PER_G) flags[i] = 0u;
}

// x f32 -> bf16, [B][T][D] layout preserved. 67108864 elems, 8 per thread.
__global__ void xconvert(const float* __restrict__ x, ushort_t* __restrict__ xb) {
  size_t i = ((size_t)blockIdx.x * 256 + threadIdx.x) * 8;
  f32x4 a = *reinterpret_cast<const f32x4*>(x + i);
  f32x4 b = *reinterpret_cast<const f32x4*>(x + i + 4);
  i32x4 o;
  o[0] = pack2(a[0], a[1]); o[1] = pack2(a[2], a[3]);
  o[2] = pack2(b[0], b[1]); o[3] = pack2(b[2], b[3]);
  *reinterpret_cast<i32x4*>(xb + i) = o;
}

// ---------------------------------------------------------------------------
// Group barrier: flag-array, agent scope. All blocks of group g set their
// slot to `target`, then poll all 64 slots. Acquire fence after.
// ---------------------------------------------------------------------------
__device__ __forceinline__ void group_barrier(unsigned* flags, int g, int slot,
                                              unsigned target, int tid) {
  __syncthreads();
  if (tid == 0) {
    __hip_atomic_store(flags + g * BLKS_PER_G + slot, target,
                       __ATOMIC_RELEASE, __HIP_MEMORY_SCOPE_AGENT);
  }
  if (tid < BLKS_PER_G) {
    while (__hip_atomic_load(flags + g * BLKS_PER_G + tid,
                             __ATOMIC_RELAXED, __HIP_MEMORY_SCOPE_AGENT) < target) {
      __builtin_amdgcn_s_sleep(2);
    }
  }
  __syncthreads();
  __builtin_amdgcn_fence(__ATOMIC_ACQUIRE, "agent");
}

// ---------------------------------------------------------------------------
// Persistent GRU. 256 blocks x 256 threads. Block bid: group g = bid>>6,
// slot = bid&63. Phase1 cols: slot*32 (of 2048); phase2 cols: slot*16 (of 1024).
// 4 waves K-split K=1536 into 384 each; weights held in VGPRs (36 short8).
// K-loop: pure global-load A-frag + MFMA (no LDS, no barriers).
// Cross-wave reduction of partial C via 32KB LDS per phase.
// ---------------------------------------------------------------------------
__global__ void __launch_bounds__(256, 1)
gru_persistent(const float* __restrict__ x, const ushort_t* __restrict__ xb,
               const int useXbf,
               const ushort_t* __restrict__ B1t, const ushort_t* __restrict__ B2t,
               ushort_t* __restrict__ hb, ushort_t* __restrict__ rhb,
               float* __restrict__ hf, float* __restrict__ zfb,
               const float* __restrict__ bb, const float* __restrict__ bz,
               const float* __restrict__ br, unsigned* __restrict__ flags,
               float* __restrict__ out) {
  __shared__ __align__(16) f32x4 redbuf[4096];   // 64KB LDS (use first 32KB)

  const int tid  = threadIdx.x;
  const int bid  = blockIdx.x;
  const int w    = tid >> 6;
  const int lane = tid & 63;
  const int l15  = lane & 15;
  const int l4   = lane >> 4;
  const int g    = bid >> 6;
  const int slot = bid & 63;
  const int n1g  = slot * 32;       // phase1 col base (0..2047)
  const int n2g  = slot * 16;       // phase2 col base (0..1023)
  const int rowbase = g * ROWS_PER_G;
  const int kw   = w * KW;
  const int kfl  = kw + 8 * l4;     // per-lane k base

  // ---- load stationary weight fragments into registers (once) ----
  short8 B1R[2][KS];
  short8 B2R[KS];
#pragma unroll
  for (int s = 0; s < KS; ++s) {
    int k = kfl + 32 * s;
#pragma unroll
    for (int j = 0; j < 2; ++j) {
      int col = n1g + 16 * j + l15;
      B1R[j][s] = *reinterpret_cast<const short8*>(B1t + (size_t)col * KK + k);
    }
    int col2 = n2g + l15;
    B2R[s] = *reinterpret_cast<const short8*>(B2t + (size_t)col2 * KK + k);
  }

  unsigned epoch = 0;

  for (int t = 0; t < NT; ++t) {
    // ================= phase 1: z | r =================
    f32x4 acc[4][2];
#pragma unroll
    for (int i = 0; i < 4; ++i)
#pragma unroll
      for (int j = 0; j < 2; ++j) acc[i][j] = (f32x4){0.f, 0.f, 0.f, 0.f};

#pragma unroll
    for (int s = 0; s < KS; ++s) {
      int k = kfl + 32 * s;
      short8 a[4];
#pragma unroll
      for (int i = 0; i < 4; ++i) {
        int row = rowbase + 16 * i + l15;
        if (k < NH) {
          a[i] = *reinterpret_cast<const short8*>(hb + (size_t)row * NH + k);
        } else {
          int kx = k - NH;
          if (useXbf) {
            a[i] = *reinterpret_cast<const short8*>(
                xb + ((size_t)row * NT + t) * ND + kx);
          } else {
            const float* xp = x + ((size_t)row * NT + t) * ND + kx;
            f32x4 f0 = *reinterpret_cast<const f32x4*>(xp);
            f32x4 f1 = *reinterpret_cast<const f32x4*>(xp + 4);
            i32x4 v;
            v[0] = pack2(f0[0], f0[1]); v[1] = pack2(f0[2], f0[3]);
            v[2] = pack2(f1[0], f1[1]); v[3] = pack2(f1[2], f1[3]);
            union { i32x4 iv; short8 sv; } u; u.iv = v;
            a[i] = u.sv;
          }
        }
      }
#pragma unroll
      for (int i = 0; i < 4; ++i)
#pragma unroll
        for (int j = 0; j < 2; ++j)
          acc[i][j] = __builtin_amdgcn_mfma_f32_16x16x32_bf16(a[i], B1R[j][s], acc[i][j], 0, 0, 0);
    }
    // ---- cross-wave reduction (K-split partials) + epilogue ----
#pragma unroll
    for (int i = 0; i < 4; ++i)
#pragma unroll
      for (int j = 0; j < 2; ++j)
        redbuf[(w * 8 + i * 2 + j) * 64 + lane] = acc[i][j];
    __syncthreads();
#pragma unroll
    for (int tt = 0; tt < 2; ++tt) {
      int tau = 2 * w + tt;               // wave w reduces tiles 2w, 2w+1
      f32x4 v = redbuf[(0 * 8 + tau) * 64 + lane];
      v += redbuf[(1 * 8 + tau) * 64 + lane];
      v += redbuf[(2 * 8 + tau) * 64 + lane];
      v += redbuf[(3 * 8 + tau) * 64 + lane];
      int i = tau >> 1, j = tau & 1;
      int cglob = n1g + 16 * j + l15;
      int r0 = rowbase + 16 * i + 4 * l4;
      if (cglob < NH) {
#pragma unroll
        for (int jj = 0; jj < 4; ++jj)
          zfb[(size_t)(r0 + jj) * NH + cglob] = sigmoidf_(v[jj] + bz[cglob]);
      } else {
        int cc = cglob - NH;
#pragma unroll
        for (int jj = 0; jj < 4; ++jj) {
          size_t idx = (size_t)(r0 + jj) * NH + cc;
          float rv = sigmoidf_(v[jj] + br[cc]);
          rhb[idx] = f2bf(rv * hf[idx]);
        }
      }
    }
    group_barrier(flags, g, slot, ++epoch, tid);

    // ================= phase 2: h_cand + update =================
    f32x4 acc2[4];
#pragma unroll
    for (int i = 0; i < 4; ++i) acc2[i] = (f32x4){0.f, 0.f, 0.f, 0.f};

#pragma unroll
    for (int s = 0; s < KS; ++s) {
      int k = kfl + 32 * s;
      short8 a[4];
#pragma unroll
      for (int i = 0; i < 4; ++i) {
        int row = rowbase + 16 * i + l15;
        if (k < NH) {
          a[i] = *reinterpret_cast<const short8*>(rhb + (size_t)row * NH + k);
        } else {
          int kx = k - NH;
          if (useXbf) {
            a[i] = *reinterpret_cast<const short8*>(
                xb + ((size_t)row * NT + t) * ND + kx);
          } else {
            const float* xp = x + ((size_t)row * NT + t) * ND + kx;
            f32x4 f0 = *reinterpret_cast<const f32x4*>(xp);
            f32x4 f1 = *reinterpret_cast<const f32x4*>(xp + 4);
            i32x4 v;
            v[0] = pack2(f0[0], f0[1]); v[1] = pack2(f0[2], f0[3]);
            v[2] = pack2(f1[0], f1[1]); v[3] = pack2(f1[2], f1[3]);
            union { i32x4 iv; short8 sv; } u; u.iv = v;
            a[i] = u.sv;
          }
        }
      }
#pragma unroll
      for (int i = 0; i < 4; ++i)
        acc2[i] = __builtin_amdgcn_mfma_f32_16x16x32_bf16(a[i], B2R[s], acc2[i], 0, 0, 0);
    }
    // ---- reduction + epilogue ----
#pragma unroll
    for (int i = 0; i < 4; ++i)
      redbuf[(w * 4 + i) * 64 + lane] = acc2[i];
    __syncthreads();
    {
      int tau = w;                        // wave w reduces tile w
      f32x4 v = redbuf[(0 * 4 + tau) * 64 + lane];
      v += redbuf[(1 * 4 + tau) * 64 + lane];
      v += redbuf[(2 * 4 + tau) * 64 + lane];
      v += redbuf[(3 * 4 + tau) * 64 + lane];
      int c = n2g + l15;
      int r0 = rowbase + 16 * w + 4 * l4;
#pragma unroll
      for (int jj = 0; jj < 4; ++jj) {
        size_t idx = (size_t)(r0 + jj) * NH + c;
        float hc = tanhf_(v[jj] + bb[c]);
        float zv = zfb[idx];
        float hn = (1.f - zv) * hf[idx] + zv * hc;
        hf[idx] = hn;
        hb[idx] = f2bf(hn);
        if (t == NT - 1) out[idx] = hn;
      }
    }
    group_barrier(flags, g, slot, ++epoch, tid);
  }
}

extern "C" void kernel_launch(void* const* d_in, const int* in_sizes, int n_in,
                              void* d_out, int out_size, void* d_ws, size_t ws_size,
                              hipStream_t stream) {
  const float* x  = (const float*)d_in[0];
  const float* W  = (const float*)d_in[1];
  const float* U  = (const float*)d_in[2];
  const float* Wz = (const float*)d_in[3];
  const float* Uz = (const float*)d_in[4];
  const float* Wr = (const float*)d_in[5];
  const float* Ur = (const float*)d_in[6];
  const float* bb = (const float*)d_in[7];
  const float* bz = (const float*)d_in[8];
  const float* br = (const float*)d_in[9];
  float* out = (float*)d_out;

  char* ws = (char*)d_ws;
  ushort_t* B1t   = (ushort_t*)(ws);                  // 6291456 B
  ushort_t* B2t   = (ushort_t*)(ws + 6291456);        // 3145728 B
  ushort_t* hb    = (ushort_t*)(ws + 9437184);        // 524288 B
  ushort_t* rhb   = (ushort_t*)(ws + 9961472);        // 524288 B
  float*    hf    = (float*)   (ws + 10485760);       // 1048576 B
  float*    zfb   = (float*)   (ws + 11534336);       // 1048576 B
  unsigned* flags = (unsigned*)(ws + 12582912);       // 4096 B
  ushort_t* xbf   = (ushort_t*)(ws + 12587008);       // 134217728 B -> end 146804736

  const int useXbf = (ws_size >= (size_t)146804736) ? 1 : 0;

  hipLaunchKernelGGL(repack_weights, dim3(24, 32, 2), dim3(256), 0, stream,
                     U, W, Uz, Wz, Ur, Wr, B1t, B2t);
  hipLaunchKernelGGL(init_state, dim3(1024), dim3(256), 0, stream, hb, hf, flags);
  if (useXbf) {
    hipLaunchKernelGGL(xconvert, dim3(32768), dim3(256), 0, stream, x, xbf);
  }
  hipLaunchKernelGGL(gru_persistent, dim3(256), dim3(256), 0, stream,
                     x, xbf, useXbf, B1t, B2t, hb, rhb, hf, zfb,
                     bb, bz, br, flags, out);
}